// Round 21
// baseline (326.004 us; speedup 1.0000x reference)
//
#include <hip/hip_runtime.h>

#define NN 20000
#define NE 640000
#define CC 128
#define HH 8
#define GG 50
#define FF 128
#define LL 3
#define NTAB 2048
#define DMAX 12.0f
#define NB 79   // (NN+255)/256 scan blocks
#define PSTR 32 // packed[] stride in ints (128B line per node counter)

typedef unsigned short u16;
typedef __attribute__((ext_vector_type(8))) short bf16x8;   // 8 bf16 = 4 VGPRs
typedef __attribute__((ext_vector_type(4))) float f32x4;

__device__ __forceinline__ u16 f2bf(float f) {
    union { unsigned int i; float f; } x; x.f = f;
    unsigned int r = x.i + 0x7fffu + ((x.i >> 16) & 1u);
    return (u16)(r >> 16);
}
// ShiftedSoftplus: softplus(x)-log2 via HW exp/log
__device__ __forceinline__ float sspf(float x) {
    return fmaxf(x, 0.0f) + __logf(1.0f + __expf(-fabsf(x))) - 0.69314718055994531f;
}

// ---------------- CSR build (sort edges by dst; far edges first per node) ------
// pos4 + zero padded counters in one kernel
__global__ void k_pos4(const float* __restrict__ pos, float4* __restrict__ pos4,
                       int* __restrict__ packed) {
    int n = blockIdx.x * 256 + threadIdx.x;
    if (n < NN) {
        float4 v;
        v.x = pos[n * 3 + 0]; v.y = pos[n * 3 + 1]; v.z = pos[n * 3 + 2]; v.w = 0.0f;
        pos4[n] = v;
        packed[(size_t)n * PSTR] = 0;
    }
}

// 4 edges/thread: distance record + rank-assigning histogram (padded counters).
// packed[b*PSTR]: lo16 = far count, hi16 = near count. Far +1 -> rank = ret&0xffff;
// near +0x10000 -> rank = ret>>16. rec2[e] = {rec, rank};
// rec = -1 (far) or (i0<<16)|frac16 (near; i0<=2046 so never -1).
__global__ void k_dist(const int* __restrict__ ei, const float4* __restrict__ pos4,
                       int* __restrict__ packed, int2* __restrict__ rec2) {
    int base = (blockIdx.x * 256 + threadIdx.x) * 4;
    if (base >= NE) return;
    int aa[4], bb[4], rec[4];
    #pragma unroll
    for (int j = 0; j < 4; ++j) {
        int e = base + j;
        aa[j] = ei[e]; bb[j] = ei[NE + e];
    }
    float4 pa[4], pb[4];
    #pragma unroll
    for (int j = 0; j < 4; ++j) { pa[j] = pos4[aa[j]]; pb[j] = pos4[bb[j]]; }
    int ret[4];
    #pragma unroll
    for (int j = 0; j < 4; ++j) {
        float dx = pb[j].x - pa[j].x, dy = pb[j].y - pa[j].y, dz = pb[j].z - pa[j].z;
        float d = sqrtf(dx * dx + dy * dy + dz * dz + 1e-12f);
        float tt = d * ((float)NTAB / DMAX);
        bool far = tt >= (float)(NTAB - 1);
        int r = -1;
        if (!far) {
            int i0 = (int)tt;
            int fr = min((int)((tt - (float)i0) * 65536.0f), 65535);
            r = (i0 << 16) | fr;
        }
        rec[j] = r;
        ret[j] = atomicAdd(&packed[(size_t)bb[j] * PSTR], far ? 1 : 0x10000);
    }
    #pragma unroll
    for (int j = 0; j < 4; ++j) {
        int rank = (rec[j] == -1) ? (ret[j] & 0xffff) : (((unsigned)ret[j]) >> 16);
        int2 o; o.x = rec[j]; o.y = rank;
        rec2[base + j] = o;
    }
}

// multi-block scan phase 1: per-block LDS scan of total counts -> pref, bsum
__global__ __launch_bounds__(256) void k_scan1(const int* __restrict__ packed,
                                               int* __restrict__ pref,
                                               int* __restrict__ bsum) {
    __shared__ int sdat[256];
    const int t = threadIdx.x;
    int n = blockIdx.x * 256 + t;
    int v = 0;
    if (n < NN) { int pk = packed[(size_t)n * PSTR]; v = (pk & 0xffff) + (int)(((unsigned)pk) >> 16); }
    sdat[t] = v;
    __syncthreads();
    for (int off = 1; off < 256; off <<= 1) {
        int u = (t >= off) ? sdat[t - off] : 0;
        __syncthreads();
        sdat[t] += u;
        __syncthreads();
    }
    if (n < NN) pref[n] = sdat[t] - v;
    if (t == 255) bsum[blockIdx.x] = sdat[255];
}

// phase 2: apply block offsets, write rowptr / rowmid (+ rowptr[NN])
__global__ __launch_bounds__(256) void k_scan2(const int* __restrict__ packed,
                                               const int* __restrict__ pref,
                                               const int* __restrict__ bsum,
                                               int* __restrict__ rowptr,
                                               int* __restrict__ rowmid) {
    __shared__ int sb[NB];
    const int t = threadIdx.x;
    if (t < NB) sb[t] = bsum[t];
    __syncthreads();
    int base = 0;
    for (int j = 0; j < blockIdx.x; ++j) base += sb[j];
    int n = blockIdx.x * 256 + t;
    if (n < NN) {
        int pk = packed[(size_t)n * PSTR];
        int r = base + pref[n];
        rowptr[n] = r;
        rowmid[n] = r + (pk & 0xffff);   // far count in lo16
    }
    if (blockIdx.x == 0 && t == 0) {
        int tot = 0;
        for (int j = 0; j < NB; ++j) tot += sb[j];
        rowptr[NN] = tot;
    }
}

// 4 edges/thread, ATOMIC-FREE scatter: pos = (far ? rowptr : rowmid)[b] + rank
__global__ void k_scatter(const int* __restrict__ ei, const int2* __restrict__ rec2,
                          const int* __restrict__ rowptr, const int* __restrict__ rowmid,
                          int* __restrict__ srcp, int2* __restrict__ erec) {
    int base = (blockIdx.x * 256 + threadIdx.x) * 4;
    if (base >= NE) return;
    int aa[4], bb[4];
    int2 rr[4];
    #pragma unroll
    for (int j = 0; j < 4; ++j) {
        int e = base + j;
        aa[j] = ei[e]; bb[j] = ei[NE + e]; rr[j] = rec2[e];
    }
    int pp[4];
    #pragma unroll
    for (int j = 0; j < 4; ++j) {
        bool far = (rr[j].x == -1);
        int b0 = far ? rowptr[bb[j]] : rowmid[bb[j]];
        pp[j] = b0 + rr[j].y;
    }
    #pragma unroll
    for (int j = 0; j < 4; ++j) {
        srcp[pp[j]] = aa[j];
        if (rr[j].x != -1) { int2 r; r.x = aa[j]; r.y = rr[j].x; erec[pp[j]] = r; }
    }
}

// ---------------- weight prep (once per call) ----------------
// W23f[l][k][cp] = sum_c w2[l][k][c] * we[l][c][cp]  (fp32)
__global__ __launch_bounds__(128) void k_prep23(const float* __restrict__ w2,
                                                const float* __restrict__ we,
                                                float* __restrict__ w23f) {
    int l = blockIdx.x >> 7, k = blockIdx.x & 127;
    int cp = threadIdx.x;
    float s = 0.0f;
    for (int c = 0; c < FF; ++c)
        s = fmaf(w2[((size_t)l * FF + k) * FF + c], we[((size_t)l * FF + c) * CC + cp], s);
    w23f[((size_t)l * FF + k) * CC + cp] = s;
}

// b23[l][cp] = be[l][cp] + sum_k b2[l][k] * we[l][k][cp]
__global__ __launch_bounds__(128) void k_prepb(const float* __restrict__ b2,
                                               const float* __restrict__ we,
                                               const float* __restrict__ be,
                                               float* __restrict__ b23g) {
    int l = blockIdx.x;
    int cp = threadIdx.x;
    float s = be[l * CC + cp];
    for (int k = 0; k < FF; ++k)
        s = fmaf(b2[l * FF + k], we[((size_t)l * FF + k) * CC + cp], s);
    b23g[l * CC + cp] = s;
}

// ep table: tab[l][i][cp] = MLP(gauss(d_i)) exact fp32, i in [0,NTAB]
__global__ __launch_bounds__(128) void k_prept(const float* __restrict__ w1,
                                               const float* __restrict__ b1,
                                               const float* __restrict__ w23f,
                                               const float* __restrict__ b23g,
                                               float* __restrict__ tab) {
    const int l = blockIdx.x / (NTAB + 1);
    const int i = blockIdx.x % (NTAB + 1);
    const int c = threadIdx.x;
    __shared__ float attr[GG];
    __shared__ float hid[FF];
    const float STEP = 10.0f / 49.0f;
    const float COEF = -0.5f / (STEP * STEP);
    float d = (float)i * (DMAX / (float)NTAB);
    if (c < GG) { float df = d - STEP * (float)c; attr[c] = __expf(COEF * df * df); }
    __syncthreads();
    float s = b1[l * FF + c];
    for (int g = 0; g < GG; ++g)
        s = fmaf(attr[g], w1[((size_t)l * GG + g) * FF + c], s);
    hid[c] = sspf(s);
    __syncthreads();
    float o = b23g[l * CC + c];
    for (int k = 0; k < FF; ++k)
        o = fmaf(hid[k], w23f[((size_t)l * FF + k) * CC + c], o);
    tab[((size_t)l * (NTAB + 1) + i) * CC + c] = o;
}

// bf16 DELTA table pairs: tabq[l][i][ln] = { bf16(tab[i]-ep_inf) pair, bf16(tab[i+1]-ep_inf) pair }
__global__ void k_packt(const float* __restrict__ tab, uint2* __restrict__ tabq) {
    int idx = blockIdx.x * 256 + threadIdx.x;
    if (idx >= LL * NTAB * 64) return;
    int ln = idx & 63;
    int i = (idx >> 6) % NTAB;
    int l = idx / (NTAB * 64);
    int c0 = ln * 2;
    const float* t0 = &tab[((size_t)l * (NTAB + 1) + i) * CC + c0];
    const float* t1 = t0 + CC;
    const float* ti = &tab[((size_t)l * (NTAB + 1) + NTAB) * CC + c0];
    uint2 o;
    o.x = (unsigned)f2bf(t0[0] - ti[0]) | ((unsigned)f2bf(t0[1] - ti[1]) << 16);
    o.y = (unsigned)f2bf(t1[0] - ti[0]) | ((unsigned)f2bf(t1[1] - ti[1]) << 16);
    tabq[((size_t)l * NTAB + i) * 64 + ln] = o;
}

// fold ep_inf into k/v biases: bkf = bk + ep_inf, bvf = bv + ep_inf
__global__ __launch_bounds__(128) void k_foldb(const float* __restrict__ bk,
                                               const float* __restrict__ bv,
                                               const float* __restrict__ tab,
                                               float* __restrict__ bkf,
                                               float* __restrict__ bvf) {
    int l = blockIdx.x, c = threadIdx.x;
    float ep = tab[((size_t)l * (NTAB + 1) + NTAB) * CC + c];
    bkf[l * CC + c] = bk[l * CC + c] + ep;
    bvf[l * CC + c] = bv[l * CC + c] + ep;
}

// node weights: wn[((l*5+m)*128 + c)*128 + k] = bf16(W_m[l][k][c]); m: q,k,v,skip,l
// plus wo1T[c64][k128] appended at offset LL*5*16384 (c<64)
__global__ void k_prepn(const float* __restrict__ wq, const float* __restrict__ wk,
                        const float* __restrict__ wv, const float* __restrict__ wsk,
                        const float* __restrict__ wl, const float* __restrict__ wo1,
                        u16* __restrict__ wn) {
    int i = blockIdx.x * 256 + threadIdx.x;
    if (i < LL * 5 * 128 * 128) {
        int k = i & 127, c = (i >> 7) & 127;
        int lm = i >> 14; int m = lm % 5, l = lm / 5;
        const float* W = (m == 0) ? wq : (m == 1) ? wk : (m == 2) ? wv : (m == 3) ? wsk : wl;
        wn[i] = f2bf(W[((size_t)l * 128 + k) * 128 + c]);
    } else if (i < LL * 5 * 128 * 128 + 64 * 128) {
        int j = i - LL * 5 * 128 * 128;
        int k = j & 127, c = j >> 7;          // c in [0,64)
        wn[i] = f2bf(wo1[k * 64 + c]);
    }
}

// ---------------- fused node kernel (64-row tiles, 313 blocks) ----------------
// MODE 0: hb <- emb[z] (also writes h);         then 4 GEMMs -> q,kvw,skip
// MODE 1: tbp(bf16) -> tb; h += tb@wl (hb <- new h); then 4 GEMMs -> q,kvw,skip
// MODE 2: tbp -> tb; newh = h + tb@wl; fused output head -> out (no h write)
// kvw layout: per node 128 u32; u32[n*128+c]=k-pair(c,c+1) even c, [+1]=v-pair.
// NOTE: k/v biases passed in are ep_inf-folded.
template<int MODE>
__global__ __launch_bounds__(256) void k_node(
    const int* __restrict__ z, const float* __restrict__ emb,
    const unsigned int* __restrict__ tbp,
    const u16* __restrict__ wlT, const float* __restrict__ bl,
    float* __restrict__ h,
    const u16* __restrict__ wq4,
    const float* __restrict__ bq, const float* __restrict__ bk,
    const float* __restrict__ bv, const float* __restrict__ bs,
    float* __restrict__ o_q, unsigned int* __restrict__ kvw,
    float* __restrict__ o_skip,
    const u16* __restrict__ wo1T, const float* __restrict__ bo1,
    const float* __restrict__ wo2, const float* __restrict__ bo2,
    float* __restrict__ outp, int nrows)
{
    __shared__ __align__(16) short tb[64 * 136];
    __shared__ __align__(16) short hb[64 * 136];
    const int t = threadIdx.x, lane = t & 63, w = t >> 6;
    const int tx = lane & 15, tg = lane >> 4;
    const int n0 = blockIdx.x * 64;
    const f32x4 zf4 = { 0.0f, 0.0f, 0.0f, 0.0f };

    if (MODE == 0) {
        for (int idx = t; idx < 64 * 32; idx += 256) {
            int r = idx >> 5, kq = idx & 31;
            int n = n0 + r;
            float4 hv;
            if (n < nrows) {
                hv = *(const float4*)&emb[(size_t)z[n] * CC + kq * 4];
                *(float4*)&h[(size_t)n * CC + kq * 4] = hv;
            } else { hv.x = hv.y = hv.z = hv.w = 0.0f; }
            uint2 pk = make_uint2((unsigned)f2bf(hv.x) | ((unsigned)f2bf(hv.y) << 16),
                                  (unsigned)f2bf(hv.z) | ((unsigned)f2bf(hv.w) << 16));
            *(uint2*)&hb[r * 136 + kq * 4] = pk;
        }
        __syncthreads();
    } else {
        // stage packed-bf16 t
        for (int idx = t; idx < 64 * 32; idx += 256) {
            int r = idx >> 5, kq = idx & 31;
            int n = n0 + r;
            uint2 pk = make_uint2(0u, 0u);
            if (n < nrows) pk = *(const uint2*)&tbp[(size_t)n * 64 + kq * 2];
            *(uint2*)&tb[r * 136 + kq * 4] = pk;
        }
        __syncthreads();
        // GEMM tb @ wl -> newh = h + .; MODE1: write h + hb; MODE2: hb only
        f32x4 acc[2][4];
        #pragma unroll
        for (int mt = 0; mt < 2; ++mt)
            #pragma unroll
            for (int nt = 0; nt < 4; ++nt) acc[mt][nt] = zf4;
        #pragma unroll
        for (int s = 0; s < 4; ++s) {
            bf16x8 af[2], bfr[4];
            #pragma unroll
            for (int mt = 0; mt < 2; ++mt)
                af[mt] = *(const bf16x8*)&wlT[(size_t)(w * 32 + mt * 16 + tx) * 128 + s * 32 + tg * 8];
            #pragma unroll
            for (int nt = 0; nt < 4; ++nt)
                bfr[nt] = *(const bf16x8*)&tb[(nt * 16 + tx) * 136 + s * 32 + tg * 8];
            #pragma unroll
            for (int mt = 0; mt < 2; ++mt)
                #pragma unroll
                for (int nt = 0; nt < 4; ++nt)
                    acc[mt][nt] = __builtin_amdgcn_mfma_f32_16x16x32_bf16(af[mt], bfr[nt], acc[mt][nt], 0, 0, 0);
        }
        #pragma unroll
        for (int mt = 0; mt < 2; ++mt) {
            int c0 = w * 32 + mt * 16 + tg * 4;
            float4 bb = *(const float4*)&bl[c0];
            #pragma unroll
            for (int nt = 0; nt < 4; ++nt) {
                int n = n0 + nt * 16 + tx;
                uint2 pk = make_uint2(0u, 0u);
                if (n < nrows) {
                    float4 hv = *(const float4*)&h[(size_t)n * 128 + c0];
                    hv.x += acc[mt][nt][0] + bb.x; hv.y += acc[mt][nt][1] + bb.y;
                    hv.z += acc[mt][nt][2] + bb.z; hv.w += acc[mt][nt][3] + bb.w;
                    if (MODE == 1) *(float4*)&h[(size_t)n * 128 + c0] = hv;
                    pk = make_uint2((unsigned)f2bf(hv.x) | ((unsigned)f2bf(hv.y) << 16),
                                    (unsigned)f2bf(hv.z) | ((unsigned)f2bf(hv.w) << 16));
                }
                *(uint2*)&hb[(nt * 16 + tx) * 136 + c0] = pk;
            }
        }
        __syncthreads();
    }

    if (MODE <= 1) {
        // 4 GEMMs from hb: m=0 q, m=1 k-pairs, m=2 v-pairs, m=3 skip
        #pragma unroll
        for (int m = 0; m < 4; ++m) {
            f32x4 acc[2][4];
            #pragma unroll
            for (int mt = 0; mt < 2; ++mt)
                #pragma unroll
                for (int nt = 0; nt < 4; ++nt) acc[mt][nt] = zf4;
            const u16* Wm = wq4 + (size_t)m * 16384;
            #pragma unroll
            for (int s = 0; s < 4; ++s) {
                bf16x8 af[2], bfr[4];
                #pragma unroll
                for (int mt = 0; mt < 2; ++mt)
                    af[mt] = *(const bf16x8*)&Wm[(size_t)(w * 32 + mt * 16 + tx) * 128 + s * 32 + tg * 8];
                #pragma unroll
                for (int nt = 0; nt < 4; ++nt)
                    bfr[nt] = *(const bf16x8*)&hb[(nt * 16 + tx) * 136 + s * 32 + tg * 8];
                #pragma unroll
                for (int mt = 0; mt < 2; ++mt)
                    #pragma unroll
                    for (int nt = 0; nt < 4; ++nt)
                        acc[mt][nt] = __builtin_amdgcn_mfma_f32_16x16x32_bf16(af[mt], bfr[nt], acc[mt][nt], 0, 0, 0);
            }
            const float* Bm = (m == 0) ? bq : (m == 1) ? bk : (m == 2) ? bv : bs;
            if (m == 0 || m == 3) {
                float* Om = (m == 0) ? o_q : o_skip;
                #pragma unroll
                for (int mt = 0; mt < 2; ++mt) {
                    int c0 = w * 32 + mt * 16 + tg * 4;
                    float4 bb = *(const float4*)&Bm[c0];
                    #pragma unroll
                    for (int nt = 0; nt < 4; ++nt) {
                        int n = n0 + nt * 16 + tx;
                        if (n < nrows) {
                            float4 ov;
                            ov.x = acc[mt][nt][0] + bb.x; ov.y = acc[mt][nt][1] + bb.y;
                            ov.z = acc[mt][nt][2] + bb.z; ov.w = acc[mt][nt][3] + bb.w;
                            *(float4*)&Om[(size_t)n * 128 + c0] = ov;
                        }
                    }
                }
            } else {
                const int off = (m == 1) ? 0 : 1;
                #pragma unroll
                for (int mt = 0; mt < 2; ++mt) {
                    int c0 = w * 32 + mt * 16 + tg * 4;
                    float4 bb = *(const float4*)&Bm[c0];
                    #pragma unroll
                    for (int nt = 0; nt < 4; ++nt) {
                        int n = n0 + nt * 16 + tx;
                        if (n < nrows) {
                            unsigned p01 = (unsigned)f2bf(acc[mt][nt][0] + bb.x)
                                         | ((unsigned)f2bf(acc[mt][nt][1] + bb.y) << 16);
                            unsigned p23 = (unsigned)f2bf(acc[mt][nt][2] + bb.z)
                                         | ((unsigned)f2bf(acc[mt][nt][3] + bb.w) << 16);
                            size_t base = (size_t)n * 128 + c0;
                            kvw[base + off] = p01;
                            kvw[base + 2 + off] = p23;
                        }
                    }
                }
            }
        }
    } else {
        // ---- fused output head: out = ssp(newh @ wo1 + bo1) @ wo2 + bo2 ----
        f32x4 acc[4];
        #pragma unroll
        for (int nt = 0; nt < 4; ++nt) acc[nt] = zf4;
        #pragma unroll
        for (int s = 0; s < 4; ++s) {
            bf16x8 af = *(const bf16x8*)&wo1T[(size_t)(w * 16 + tx) * 128 + s * 32 + tg * 8];
            bf16x8 bfr[4];
            #pragma unroll
            for (int nt = 0; nt < 4; ++nt)
                bfr[nt] = *(const bf16x8*)&hb[(nt * 16 + tx) * 136 + s * 32 + tg * 8];
            #pragma unroll
            for (int nt = 0; nt < 4; ++nt)
                acc[nt] = __builtin_amdgcn_mfma_f32_16x16x32_bf16(af, bfr[nt], acc[nt], 0, 0, 0);
        }
        __syncthreads();          // tb LDS is dead; reuse as f32 hsum[4][64]
        float* hsum = (float*)tb;
        #pragma unroll
        for (int nt = 0; nt < 4; ++nt) {
            int c0 = w * 16 + tg * 4;
            float4 b1v = *(const float4*)&bo1[c0];
            float4 w2v = *(const float4*)&wo2[c0];
            float pl = sspf(acc[nt][0] + b1v.x) * w2v.x
                     + sspf(acc[nt][1] + b1v.y) * w2v.y
                     + sspf(acc[nt][2] + b1v.z) * w2v.z
                     + sspf(acc[nt][3] + b1v.w) * w2v.w;
            pl += __shfl_xor(pl, 16);
            pl += __shfl_xor(pl, 32);
            if (tg == 0) hsum[w * 64 + nt * 16 + tx] = pl;
        }
        __syncthreads();
        if (t < 64) {
            int n = n0 + t;
            if (n < nrows)
                outp[n] = hsum[t] + hsum[64 + t] + hsum[128 + t] + hsum[192 + t] + bo2[0];
        }
    }
}

// ---------------- node-centric edge aggregation --------------------------------
// One wave per dst node; 2 channels/lane. Edges sorted far-first per node.
// Far edge (d>=DMAX): ep folded into kvw biases -> 1 kv gather + dot + exp.
// Near edge: + bf16 delta-table lerp. q pre-scaled by 0.25*log2(e); exp2f.
// Output t is packed bf16 pairs.
__global__ __launch_bounds__(256) void k_agg(
    const int* __restrict__ rowptr, const int* __restrict__ rowmid,
    const int* __restrict__ srcp, const int2* __restrict__ erec,
    const uint2* __restrict__ tabq, const float* __restrict__ qn,
    const unsigned int* __restrict__ kvw, const float* __restrict__ skip,
    unsigned int* __restrict__ tout)
{
    int wid0 = (blockIdx.x * 256 + threadIdx.x) >> 6;   // node id
    if (wid0 >= NN) return;
    const int wid = __builtin_amdgcn_readfirstlane(wid0);   // SGPR -> scalar loads
    const int ln = threadIdx.x & 63;
    const int c0 = ln * 2;   // head = ln>>3
    const float SC = 0.25f * 1.4426950408889634f;
    float2 q2 = *(const float2*)&qn[(size_t)wid * CC + c0];
    q2.x *= SC; q2.y *= SC;
    float nx = 0.0f, ny = 0.0f, den = 0.0f;
    int e = rowptr[wid];
    const int emid = rowmid[wid];
    const int eend = rowptr[wid + 1];
    const float FS = 1.52587890625e-5f;   // 1/65536

    auto edgeF = [&](uint2 kv) {
        float kex = __uint_as_float(kv.x << 16);
        float key = __uint_as_float(kv.x & 0xffff0000u);
        float vex = __uint_as_float(kv.y << 16);
        float vey = __uint_as_float(kv.y & 0xffff0000u);
        float p = fmaf(q2.x, kex, q2.y * key);
        p += __shfl_xor(p, 1);
        p += __shfl_xor(p, 2);
        p += __shfl_xor(p, 4);          // sum over the head's 16 channels
        float w = exp2f(p);
        nx = fmaf(w, vex, nx);
        ny = fmaf(w, vey, ny);
        den += w;
    };
    auto edgeN = [&](uint2 kv, uint2 tp, float fr) {
        float t0x = __uint_as_float(tp.x << 16);
        float t0y = __uint_as_float(tp.x & 0xffff0000u);
        float t1x = __uint_as_float(tp.y << 16);
        float t1y = __uint_as_float(tp.y & 0xffff0000u);
        float ex = fmaf(fr, t1x - t0x, t0x);
        float ey = fmaf(fr, t1y - t0y, t0y);
        float kex = __uint_as_float(kv.x << 16) + ex;
        float key = __uint_as_float(kv.x & 0xffff0000u) + ey;
        float vex = __uint_as_float(kv.y << 16) + ex;
        float vey = __uint_as_float(kv.y & 0xffff0000u) + ey;
        float p = fmaf(q2.x, kex, q2.y * key);
        p += __shfl_xor(p, 1);
        p += __shfl_xor(p, 2);
        p += __shfl_xor(p, 4);
        float w = exp2f(p);
        nx = fmaf(w, vex, nx);
        ny = fmaf(w, vey, ny);
        den += w;
    };

    // ---- far edges, 16-deep then 8-deep then singles ----
    for (; e + 16 <= emid; e += 16) {
        int ss[16];
        #pragma unroll
        for (int j = 0; j < 16; ++j) ss[j] = srcp[e + j];
        uint2 kvv[16];
        #pragma unroll
        for (int j = 0; j < 16; ++j) kvv[j] = *(const uint2*)&kvw[(size_t)ss[j] * 128 + c0];
        #pragma unroll
        for (int j = 0; j < 16; ++j) edgeF(kvv[j]);
    }
    for (; e + 8 <= emid; e += 8) {
        int ss[8];
        #pragma unroll
        for (int j = 0; j < 8; ++j) ss[j] = srcp[e + j];
        uint2 kvv[8];
        #pragma unroll
        for (int j = 0; j < 8; ++j) kvv[j] = *(const uint2*)&kvw[(size_t)ss[j] * 128 + c0];
        #pragma unroll
        for (int j = 0; j < 8; ++j) edgeF(kvv[j]);
    }
    for (; e < emid; ++e) {
        uint2 kv = *(const uint2*)&kvw[(size_t)srcp[e] * 128 + c0];
        edgeF(kv);
    }
    // ---- near edges, 4-deep ----
    for (; e + 4 <= eend; e += 4) {
        int2 r0 = erec[e + 0], r1 = erec[e + 1], r2 = erec[e + 2], r3 = erec[e + 3];
        uint2 kv0 = *(const uint2*)&kvw[(size_t)r0.x * 128 + c0];
        uint2 kv1 = *(const uint2*)&kvw[(size_t)r1.x * 128 + c0];
        uint2 kv2 = *(const uint2*)&kvw[(size_t)r2.x * 128 + c0];
        uint2 kv3 = *(const uint2*)&kvw[(size_t)r3.x * 128 + c0];
        uint2 tp0 = tabq[(size_t)(r0.y >> 16) * 64 + ln];
        uint2 tp1 = tabq[(size_t)(r1.y >> 16) * 64 + ln];
        uint2 tp2 = tabq[(size_t)(r2.y >> 16) * 64 + ln];
        uint2 tp3 = tabq[(size_t)(r3.y >> 16) * 64 + ln];
        edgeN(kv0, tp0, (float)(r0.y & 0xffff) * FS);
        edgeN(kv1, tp1, (float)(r1.y & 0xffff) * FS);
        edgeN(kv2, tp2, (float)(r2.y & 0xffff) * FS);
        edgeN(kv3, tp3, (float)(r3.y & 0xffff) * FS);
    }
    for (; e < eend; ++e) {
        int2 r = erec[e];
        uint2 kv = *(const uint2*)&kvw[(size_t)r.x * 128 + c0];
        uint2 tp = tabq[(size_t)(r.y >> 16) * 64 + ln];
        edgeN(kv, tp, (float)(r.y & 0xffff) * FS);
    }

    const float2 sk = *(const float2*)&skip[(size_t)wid * CC + c0];
    float inv = 1.0f / (den + 1e-16f);
    float ox = sspf(fmaf(nx, inv, sk.x));
    float oy = sspf(fmaf(ny, inv, sk.y));
    tout[(size_t)wid * 64 + ln] = (unsigned)f2bf(ox) | ((unsigned)f2bf(oy) << 16);
}

extern "C" void kernel_launch(void* const* d_in, const int* in_sizes, int n_in,
                              void* d_out, int out_size, void* d_ws, size_t ws_size,
                              hipStream_t stream)
{
    const int*   z   = (const int*)d_in[0];
    const float* pos = (const float*)d_in[1];
    const int*   ei  = (const int*)d_in[2];
    const float* emb = (const float*)d_in[3];
    const float* w1  = (const float*)d_in[4];
    const float* b1  = (const float*)d_in[5];
    const float* w2  = (const float*)d_in[6];
    const float* b2  = (const float*)d_in[7];
    const float* wq  = (const float*)d_in[8];
    const float* bq  = (const float*)d_in[9];
    const float* wk  = (const float*)d_in[10];
    const float* bk  = (const float*)d_in[11];
    const float* wv  = (const float*)d_in[12];
    const float* bv  = (const float*)d_in[13];
    const float* we  = (const float*)d_in[14];
    const float* be  = (const float*)d_in[15];
    const float* wsk = (const float*)d_in[16];
    const float* bsk = (const float*)d_in[17];
    const float* wl  = (const float*)d_in[18];
    const float* bl  = (const float*)d_in[19];
    const float* wo1 = (const float*)d_in[20];
    const float* bo1 = (const float*)d_in[21];
    const float* wo2 = (const float*)d_in[22];
    const float* bo2 = (const float*)d_in[23];

    char* p = (char*)d_ws;
    auto alloc = [&](size_t bytes) -> void* {
        void* r = (void*)p; p += (bytes + 255) & ~(size_t)255; return r;
    };
    float* h    = (float*)alloc((size_t)NN * CC * 4);
    float* q    = (float*)alloc((size_t)NN * CC * 4);
    float* skip = (float*)alloc((size_t)NN * CC * 4);
    unsigned int* tbp = (unsigned int*)alloc((size_t)NN * 64 * 4);   // packed bf16 t
    unsigned int* kvw = (unsigned int*)alloc((size_t)NN * 128 * 4);  // bf16 k/v pairs
    float4* pos4 = (float4*)alloc((size_t)NN * 16);
    float* w23f = (float*)alloc((size_t)LL * FF * CC * 4);
    float* b23g = (float*)alloc((size_t)LL * CC * 4);
    float* tab  = (float*)alloc((size_t)LL * (NTAB + 1) * CC * 4);
    uint2* tabq = (uint2*)alloc((size_t)LL * NTAB * 64 * 8);
    float* bkf  = (float*)alloc((size_t)LL * CC * 4);
    float* bvf  = (float*)alloc((size_t)LL * CC * 4);
    u16*   wn   = (u16*)alloc(((size_t)LL * 5 * 128 * 128 + 64 * 128) * 2);
    int* packed = (int*)alloc((size_t)NN * PSTR * 4);   // 128B line per counter
    int* pref   = (int*)alloc((size_t)NN * 4);
    int* bsum   = (int*)alloc((size_t)NB * 4);
    int* rowptr = (int*)alloc((size_t)(NN + 1) * 4);
    int* rowmid = (int*)alloc((size_t)NN * 4);
    int* srcp   = (int*)alloc((size_t)NE * 4);
    int2* rec2  = (int2*)alloc((size_t)NE * 8);
    int2* erec  = (int2*)alloc((size_t)NE * 8);

    k_pos4<<<(NN + 255) / 256, 256, 0, stream>>>(pos, pos4, packed);
    k_dist<<<(NE / 4 + 255) / 256, 256, 0, stream>>>(ei, pos4, packed, rec2);
    k_scan1<<<NB, 256, 0, stream>>>(packed, pref, bsum);
    k_scan2<<<NB, 256, 0, stream>>>(packed, pref, bsum, rowptr, rowmid);
    k_scatter<<<(NE / 4 + 255) / 256, 256, 0, stream>>>(ei, rec2, rowptr, rowmid, srcp, erec);
    k_prep23<<<LL * 128, 128, 0, stream>>>(w2, we, w23f);
    k_prepb<<<LL, 128, 0, stream>>>(b2, we, be, b23g);
    k_prept<<<LL * (NTAB + 1), 128, 0, stream>>>(w1, b1, w23f, b23g, tab);
    k_packt<<<(LL * NTAB * 64 + 255) / 256, 256, 0, stream>>>(tab, tabq);
    k_foldb<<<LL, 128, 0, stream>>>(bk, bv, tab, bkf, bvf);
    k_prepn<<<(LL * 5 * 128 * 128 + 64 * 128 + 255) / 256, 256, 0, stream>>>(
        wq, wk, wv, wsk, wl, wo1, wn);

    const u16* wo1T = wn + (size_t)LL * 5 * 16384;
    const int NT = (NN + 63) / 64;   // 313
    // layer 0 q/k/v/skip from emb[z] (writes h too)
    k_node<0><<<NT, 256, 0, stream>>>(z, emb, nullptr, nullptr, nullptr, h,
        wn, bq, bkf, bvf, bsk, q, kvw, skip,
        nullptr, nullptr, nullptr, nullptr, nullptr, NN);
    for (int l = 0; l < LL; ++l) {
        k_agg<<<(NN * 64 + 255) / 256, 256, 0, stream>>>(rowptr, rowmid, srcp, erec,
            tabq + (size_t)l * NTAB * 64, q, kvw, skip, tbp);
        const u16* wnl = wn + (size_t)l * 5 * 16384;
        if (l < LL - 1) {
            const u16* wnn = wn + (size_t)(l + 1) * 5 * 16384;
            k_node<1><<<NT, 256, 0, stream>>>(nullptr, nullptr, tbp,
                wnl + 4 * 16384, bl + l * CC, h,
                wnn, bq + (l + 1) * CC, bkf + (l + 1) * CC,
                bvf + (l + 1) * CC, bsk + (l + 1) * CC,
                q, kvw, skip,
                nullptr, nullptr, nullptr, nullptr, nullptr, NN);
        } else {
            k_node<2><<<NT, 256, 0, stream>>>(nullptr, nullptr, tbp,
                wnl + 4 * 16384, bl + l * CC, h,
                nullptr, nullptr, nullptr, nullptr, nullptr,
                nullptr, nullptr, nullptr,
                wo1T, bo1, wo2, bo2, (float*)d_out, NN);
        }
    }
}

// Round 22
// 310.334 us; speedup vs baseline: 1.0505x; 1.0505x over previous
//
#include <hip/hip_runtime.h>

#define NN 20000
#define NE 640000
#define CC 128
#define HH 8
#define GG 50
#define FF 128
#define LL 3
#define NTAB 2048
#define DMAX 12.0f
#define NB 79   // (NN+255)/256 scan blocks
#define PSTR 32 // packed[] stride in ints (128B line per node counter)

typedef unsigned short u16;
typedef __attribute__((ext_vector_type(8))) short bf16x8;   // 8 bf16 = 4 VGPRs
typedef __attribute__((ext_vector_type(4))) float f32x4;

__device__ __forceinline__ u16 f2bf(float f) {
    union { unsigned int i; float f; } x; x.f = f;
    unsigned int r = x.i + 0x7fffu + ((x.i >> 16) & 1u);
    return (u16)(r >> 16);
}
// ShiftedSoftplus: softplus(x)-log2 via HW exp/log
__device__ __forceinline__ float sspf(float x) {
    return fmaxf(x, 0.0f) + __logf(1.0f + __expf(-fabsf(x))) - 0.69314718055994531f;
}

// ---------------- CSR build (sort edges by dst; far edges first per node) ------
// pos4 + zero padded counters in one kernel
__global__ void k_pos4(const float* __restrict__ pos, float4* __restrict__ pos4,
                       int* __restrict__ packed) {
    int n = blockIdx.x * 256 + threadIdx.x;
    if (n < NN) {
        float4 v;
        v.x = pos[n * 3 + 0]; v.y = pos[n * 3 + 1]; v.z = pos[n * 3 + 2]; v.w = 0.0f;
        pos4[n] = v;
        packed[(size_t)n * PSTR] = 0;
    }
}

// 4 edges/thread: distance record + rank-assigning histogram (padded counters).
// packed[b*PSTR]: lo16 = far count, hi16 = near count. Far +1 -> rank = ret&0xffff;
// near +0x10000 -> rank = ret>>16. rec2[e] = {rec, rank};
// rec = -1 (far) or (i0<<16)|frac16 (near; i0<=2046 so never -1).
__global__ void k_dist(const int* __restrict__ ei, const float4* __restrict__ pos4,
                       int* __restrict__ packed, int2* __restrict__ rec2) {
    int base = (blockIdx.x * 256 + threadIdx.x) * 4;
    if (base >= NE) return;
    int aa[4], bb[4], rec[4];
    #pragma unroll
    for (int j = 0; j < 4; ++j) {
        int e = base + j;
        aa[j] = ei[e]; bb[j] = ei[NE + e];
    }
    float4 pa[4], pb[4];
    #pragma unroll
    for (int j = 0; j < 4; ++j) { pa[j] = pos4[aa[j]]; pb[j] = pos4[bb[j]]; }
    int ret[4];
    #pragma unroll
    for (int j = 0; j < 4; ++j) {
        float dx = pb[j].x - pa[j].x, dy = pb[j].y - pa[j].y, dz = pb[j].z - pa[j].z;
        float d = sqrtf(dx * dx + dy * dy + dz * dz + 1e-12f);
        float tt = d * ((float)NTAB / DMAX);
        bool far = tt >= (float)(NTAB - 1);
        int r = -1;
        if (!far) {
            int i0 = (int)tt;
            int fr = min((int)((tt - (float)i0) * 65536.0f), 65535);
            r = (i0 << 16) | fr;
        }
        rec[j] = r;
        ret[j] = atomicAdd(&packed[(size_t)bb[j] * PSTR], far ? 1 : 0x10000);
    }
    #pragma unroll
    for (int j = 0; j < 4; ++j) {
        int rank = (rec[j] == -1) ? (ret[j] & 0xffff) : (((unsigned)ret[j]) >> 16);
        int2 o; o.x = rec[j]; o.y = rank;
        rec2[base + j] = o;
    }
}

// multi-block scan phase 1: per-block LDS scan of total counts -> pref, bsum
__global__ __launch_bounds__(256) void k_scan1(const int* __restrict__ packed,
                                               int* __restrict__ pref,
                                               int* __restrict__ bsum) {
    __shared__ int sdat[256];
    const int t = threadIdx.x;
    int n = blockIdx.x * 256 + t;
    int v = 0;
    if (n < NN) { int pk = packed[(size_t)n * PSTR]; v = (pk & 0xffff) + (int)(((unsigned)pk) >> 16); }
    sdat[t] = v;
    __syncthreads();
    for (int off = 1; off < 256; off <<= 1) {
        int u = (t >= off) ? sdat[t - off] : 0;
        __syncthreads();
        sdat[t] += u;
        __syncthreads();
    }
    if (n < NN) pref[n] = sdat[t] - v;
    if (t == 255) bsum[blockIdx.x] = sdat[255];
}

// phase 2: apply block offsets, write rowptr / rowmid (+ rowptr[NN])
__global__ __launch_bounds__(256) void k_scan2(const int* __restrict__ packed,
                                               const int* __restrict__ pref,
                                               const int* __restrict__ bsum,
                                               int* __restrict__ rowptr,
                                               int* __restrict__ rowmid) {
    __shared__ int sb[NB];
    const int t = threadIdx.x;
    if (t < NB) sb[t] = bsum[t];
    __syncthreads();
    int base = 0;
    for (int j = 0; j < blockIdx.x; ++j) base += sb[j];
    int n = blockIdx.x * 256 + t;
    if (n < NN) {
        int pk = packed[(size_t)n * PSTR];
        int r = base + pref[n];
        rowptr[n] = r;
        rowmid[n] = r + (pk & 0xffff);   // far count in lo16
    }
    if (blockIdx.x == 0 && t == 0) {
        int tot = 0;
        for (int j = 0; j < NB; ++j) tot += sb[j];
        rowptr[NN] = tot;
    }
}

// 4 edges/thread, ATOMIC-FREE scatter: pos = (far ? rowptr : rowmid)[b] + rank
__global__ void k_scatter(const int* __restrict__ ei, const int2* __restrict__ rec2,
                          const int* __restrict__ rowptr, const int* __restrict__ rowmid,
                          int* __restrict__ srcp, int2* __restrict__ erec) {
    int base = (blockIdx.x * 256 + threadIdx.x) * 4;
    if (base >= NE) return;
    int aa[4], bb[4];
    int2 rr[4];
    #pragma unroll
    for (int j = 0; j < 4; ++j) {
        int e = base + j;
        aa[j] = ei[e]; bb[j] = ei[NE + e]; rr[j] = rec2[e];
    }
    int pp[4];
    #pragma unroll
    for (int j = 0; j < 4; ++j) {
        bool far = (rr[j].x == -1);
        int b0 = far ? rowptr[bb[j]] : rowmid[bb[j]];
        pp[j] = b0 + rr[j].y;
    }
    #pragma unroll
    for (int j = 0; j < 4; ++j) {
        srcp[pp[j]] = aa[j];
        if (rr[j].x != -1) { int2 r; r.x = aa[j]; r.y = rr[j].x; erec[pp[j]] = r; }
    }
}

// ---------------- weight prep (once per call) ----------------
// W23f[l][k][cp] = sum_c w2[l][k][c] * we[l][c][cp]  (fp32)
__global__ __launch_bounds__(128) void k_prep23(const float* __restrict__ w2,
                                                const float* __restrict__ we,
                                                float* __restrict__ w23f) {
    int l = blockIdx.x >> 7, k = blockIdx.x & 127;
    int cp = threadIdx.x;
    float s = 0.0f;
    for (int c = 0; c < FF; ++c)
        s = fmaf(w2[((size_t)l * FF + k) * FF + c], we[((size_t)l * FF + c) * CC + cp], s);
    w23f[((size_t)l * FF + k) * CC + cp] = s;
}

// b23[l][cp] = be[l][cp] + sum_k b2[l][k] * we[l][k][cp]
__global__ __launch_bounds__(128) void k_prepb(const float* __restrict__ b2,
                                               const float* __restrict__ we,
                                               const float* __restrict__ be,
                                               float* __restrict__ b23g) {
    int l = blockIdx.x;
    int cp = threadIdx.x;
    float s = be[l * CC + cp];
    for (int k = 0; k < FF; ++k)
        s = fmaf(b2[l * FF + k], we[((size_t)l * FF + k) * CC + cp], s);
    b23g[l * CC + cp] = s;
}

// ep table: tab[l][i][cp] = MLP(gauss(d_i)) exact fp32, i in [0,NTAB]
__global__ __launch_bounds__(128) void k_prept(const float* __restrict__ w1,
                                               const float* __restrict__ b1,
                                               const float* __restrict__ w23f,
                                               const float* __restrict__ b23g,
                                               float* __restrict__ tab) {
    const int l = blockIdx.x / (NTAB + 1);
    const int i = blockIdx.x % (NTAB + 1);
    const int c = threadIdx.x;
    __shared__ float attr[GG];
    __shared__ float hid[FF];
    const float STEP = 10.0f / 49.0f;
    const float COEF = -0.5f / (STEP * STEP);
    float d = (float)i * (DMAX / (float)NTAB);
    if (c < GG) { float df = d - STEP * (float)c; attr[c] = __expf(COEF * df * df); }
    __syncthreads();
    float s = b1[l * FF + c];
    for (int g = 0; g < GG; ++g)
        s = fmaf(attr[g], w1[((size_t)l * GG + g) * FF + c], s);
    hid[c] = sspf(s);
    __syncthreads();
    float o = b23g[l * CC + c];
    for (int k = 0; k < FF; ++k)
        o = fmaf(hid[k], w23f[((size_t)l * FF + k) * CC + c], o);
    tab[((size_t)l * (NTAB + 1) + i) * CC + c] = o;
}

// bf16 DELTA table pairs: tabq[l][i][ln] = { bf16(tab[i]-ep_inf) pair, bf16(tab[i+1]-ep_inf) pair }
__global__ void k_packt(const float* __restrict__ tab, uint2* __restrict__ tabq) {
    int idx = blockIdx.x * 256 + threadIdx.x;
    if (idx >= LL * NTAB * 64) return;
    int ln = idx & 63;
    int i = (idx >> 6) % NTAB;
    int l = idx / (NTAB * 64);
    int c0 = ln * 2;
    const float* t0 = &tab[((size_t)l * (NTAB + 1) + i) * CC + c0];
    const float* t1 = t0 + CC;
    const float* ti = &tab[((size_t)l * (NTAB + 1) + NTAB) * CC + c0];
    uint2 o;
    o.x = (unsigned)f2bf(t0[0] - ti[0]) | ((unsigned)f2bf(t0[1] - ti[1]) << 16);
    o.y = (unsigned)f2bf(t1[0] - ti[0]) | ((unsigned)f2bf(t1[1] - ti[1]) << 16);
    tabq[((size_t)l * NTAB + i) * 64 + ln] = o;
}

// fold ep_inf into k/v biases: bkf = bk + ep_inf, bvf = bv + ep_inf
__global__ __launch_bounds__(128) void k_foldb(const float* __restrict__ bk,
                                               const float* __restrict__ bv,
                                               const float* __restrict__ tab,
                                               float* __restrict__ bkf,
                                               float* __restrict__ bvf) {
    int l = blockIdx.x, c = threadIdx.x;
    float ep = tab[((size_t)l * (NTAB + 1) + NTAB) * CC + c];
    bkf[l * CC + c] = bk[l * CC + c] + ep;
    bvf[l * CC + c] = bv[l * CC + c] + ep;
}

// node weights: wn[((l*5+m)*128 + c)*128 + k] = bf16(W_m[l][k][c]); m: q,k,v,skip,l
// plus wo1T[c64][k128] appended at offset LL*5*16384 (c<64)
__global__ void k_prepn(const float* __restrict__ wq, const float* __restrict__ wk,
                        const float* __restrict__ wv, const float* __restrict__ wsk,
                        const float* __restrict__ wl, const float* __restrict__ wo1,
                        u16* __restrict__ wn) {
    int i = blockIdx.x * 256 + threadIdx.x;
    if (i < LL * 5 * 128 * 128) {
        int k = i & 127, c = (i >> 7) & 127;
        int lm = i >> 14; int m = lm % 5, l = lm / 5;
        const float* W = (m == 0) ? wq : (m == 1) ? wk : (m == 2) ? wv : (m == 3) ? wsk : wl;
        wn[i] = f2bf(W[((size_t)l * 128 + k) * 128 + c]);
    } else if (i < LL * 5 * 128 * 128 + 64 * 128) {
        int j = i - LL * 5 * 128 * 128;
        int k = j & 127, c = j >> 7;          // c in [0,64)
        wn[i] = f2bf(wo1[k * 64 + c]);
    }
}

// ---------------- fused node kernel (64-row tiles, 313 blocks) ----------------
// MODE 0: hb <- emb[z] (also writes h);         then 4 GEMMs -> q,kvw,skip
// MODE 1: tbp(bf16) -> tb; h += tb@wl (hb <- new h); then 4 GEMMs -> q,kvw,skip
// MODE 2: tbp -> tb; newh = h + tb@wl; fused output head -> out (no h write)
// kvw layout: per node 128 u32; u32[n*128+c]=k-pair(c,c+1) even c, [+1]=v-pair.
// NOTE: k/v biases passed in are ep_inf-folded.
template<int MODE>
__global__ __launch_bounds__(256) void k_node(
    const int* __restrict__ z, const float* __restrict__ emb,
    const unsigned int* __restrict__ tbp,
    const u16* __restrict__ wlT, const float* __restrict__ bl,
    float* __restrict__ h,
    const u16* __restrict__ wq4,
    const float* __restrict__ bq, const float* __restrict__ bk,
    const float* __restrict__ bv, const float* __restrict__ bs,
    float* __restrict__ o_q, unsigned int* __restrict__ kvw,
    float* __restrict__ o_skip,
    const u16* __restrict__ wo1T, const float* __restrict__ bo1,
    const float* __restrict__ wo2, const float* __restrict__ bo2,
    float* __restrict__ outp, int nrows)
{
    __shared__ __align__(16) short tb[64 * 136];
    __shared__ __align__(16) short hb[64 * 136];
    const int t = threadIdx.x, lane = t & 63, w = t >> 6;
    const int tx = lane & 15, tg = lane >> 4;
    const int n0 = blockIdx.x * 64;
    const f32x4 zf4 = { 0.0f, 0.0f, 0.0f, 0.0f };

    if (MODE == 0) {
        for (int idx = t; idx < 64 * 32; idx += 256) {
            int r = idx >> 5, kq = idx & 31;
            int n = n0 + r;
            float4 hv;
            if (n < nrows) {
                hv = *(const float4*)&emb[(size_t)z[n] * CC + kq * 4];
                *(float4*)&h[(size_t)n * CC + kq * 4] = hv;
            } else { hv.x = hv.y = hv.z = hv.w = 0.0f; }
            uint2 pk = make_uint2((unsigned)f2bf(hv.x) | ((unsigned)f2bf(hv.y) << 16),
                                  (unsigned)f2bf(hv.z) | ((unsigned)f2bf(hv.w) << 16));
            *(uint2*)&hb[r * 136 + kq * 4] = pk;
        }
        __syncthreads();
    } else {
        // stage packed-bf16 t
        for (int idx = t; idx < 64 * 32; idx += 256) {
            int r = idx >> 5, kq = idx & 31;
            int n = n0 + r;
            uint2 pk = make_uint2(0u, 0u);
            if (n < nrows) pk = *(const uint2*)&tbp[(size_t)n * 64 + kq * 2];
            *(uint2*)&tb[r * 136 + kq * 4] = pk;
        }
        __syncthreads();
        // GEMM tb @ wl -> newh = h + .; MODE1: write h + hb; MODE2: hb only
        f32x4 acc[2][4];
        #pragma unroll
        for (int mt = 0; mt < 2; ++mt)
            #pragma unroll
            for (int nt = 0; nt < 4; ++nt) acc[mt][nt] = zf4;
        #pragma unroll
        for (int s = 0; s < 4; ++s) {
            bf16x8 af[2], bfr[4];
            #pragma unroll
            for (int mt = 0; mt < 2; ++mt)
                af[mt] = *(const bf16x8*)&wlT[(size_t)(w * 32 + mt * 16 + tx) * 128 + s * 32 + tg * 8];
            #pragma unroll
            for (int nt = 0; nt < 4; ++nt)
                bfr[nt] = *(const bf16x8*)&tb[(nt * 16 + tx) * 136 + s * 32 + tg * 8];
            #pragma unroll
            for (int mt = 0; mt < 2; ++mt)
                #pragma unroll
                for (int nt = 0; nt < 4; ++nt)
                    acc[mt][nt] = __builtin_amdgcn_mfma_f32_16x16x32_bf16(af[mt], bfr[nt], acc[mt][nt], 0, 0, 0);
        }
        #pragma unroll
        for (int mt = 0; mt < 2; ++mt) {
            int c0 = w * 32 + mt * 16 + tg * 4;
            float4 bb = *(const float4*)&bl[c0];
            #pragma unroll
            for (int nt = 0; nt < 4; ++nt) {
                int n = n0 + nt * 16 + tx;
                uint2 pk = make_uint2(0u, 0u);
                if (n < nrows) {
                    float4 hv = *(const float4*)&h[(size_t)n * 128 + c0];
                    hv.x += acc[mt][nt][0] + bb.x; hv.y += acc[mt][nt][1] + bb.y;
                    hv.z += acc[mt][nt][2] + bb.z; hv.w += acc[mt][nt][3] + bb.w;
                    if (MODE == 1) *(float4*)&h[(size_t)n * 128 + c0] = hv;
                    pk = make_uint2((unsigned)f2bf(hv.x) | ((unsigned)f2bf(hv.y) << 16),
                                    (unsigned)f2bf(hv.z) | ((unsigned)f2bf(hv.w) << 16));
                }
                *(uint2*)&hb[(nt * 16 + tx) * 136 + c0] = pk;
            }
        }
        __syncthreads();
    }

    if (MODE <= 1) {
        // 4 GEMMs from hb: m=0 q, m=1 k-pairs, m=2 v-pairs, m=3 skip
        #pragma unroll
        for (int m = 0; m < 4; ++m) {
            f32x4 acc[2][4];
            #pragma unroll
            for (int mt = 0; mt < 2; ++mt)
                #pragma unroll
                for (int nt = 0; nt < 4; ++nt) acc[mt][nt] = zf4;
            const u16* Wm = wq4 + (size_t)m * 16384;
            #pragma unroll
            for (int s = 0; s < 4; ++s) {
                bf16x8 af[2], bfr[4];
                #pragma unroll
                for (int mt = 0; mt < 2; ++mt)
                    af[mt] = *(const bf16x8*)&Wm[(size_t)(w * 32 + mt * 16 + tx) * 128 + s * 32 + tg * 8];
                #pragma unroll
                for (int nt = 0; nt < 4; ++nt)
                    bfr[nt] = *(const bf16x8*)&hb[(nt * 16 + tx) * 136 + s * 32 + tg * 8];
                #pragma unroll
                for (int mt = 0; mt < 2; ++mt)
                    #pragma unroll
                    for (int nt = 0; nt < 4; ++nt)
                        acc[mt][nt] = __builtin_amdgcn_mfma_f32_16x16x32_bf16(af[mt], bfr[nt], acc[mt][nt], 0, 0, 0);
            }
            const float* Bm = (m == 0) ? bq : (m == 1) ? bk : (m == 2) ? bv : bs;
            if (m == 0 || m == 3) {
                float* Om = (m == 0) ? o_q : o_skip;
                #pragma unroll
                for (int mt = 0; mt < 2; ++mt) {
                    int c0 = w * 32 + mt * 16 + tg * 4;
                    float4 bb = *(const float4*)&Bm[c0];
                    #pragma unroll
                    for (int nt = 0; nt < 4; ++nt) {
                        int n = n0 + nt * 16 + tx;
                        if (n < nrows) {
                            float4 ov;
                            ov.x = acc[mt][nt][0] + bb.x; ov.y = acc[mt][nt][1] + bb.y;
                            ov.z = acc[mt][nt][2] + bb.z; ov.w = acc[mt][nt][3] + bb.w;
                            *(float4*)&Om[(size_t)n * 128 + c0] = ov;
                        }
                    }
                }
            } else {
                const int off = (m == 1) ? 0 : 1;
                #pragma unroll
                for (int mt = 0; mt < 2; ++mt) {
                    int c0 = w * 32 + mt * 16 + tg * 4;
                    float4 bb = *(const float4*)&Bm[c0];
                    #pragma unroll
                    for (int nt = 0; nt < 4; ++nt) {
                        int n = n0 + nt * 16 + tx;
                        if (n < nrows) {
                            unsigned p01 = (unsigned)f2bf(acc[mt][nt][0] + bb.x)
                                         | ((unsigned)f2bf(acc[mt][nt][1] + bb.y) << 16);
                            unsigned p23 = (unsigned)f2bf(acc[mt][nt][2] + bb.z)
                                         | ((unsigned)f2bf(acc[mt][nt][3] + bb.w) << 16);
                            size_t base = (size_t)n * 128 + c0;
                            kvw[base + off] = p01;
                            kvw[base + 2 + off] = p23;
                        }
                    }
                }
            }
        }
    } else {
        // ---- fused output head: out = ssp(newh @ wo1 + bo1) @ wo2 + bo2 ----
        f32x4 acc[4];
        #pragma unroll
        for (int nt = 0; nt < 4; ++nt) acc[nt] = zf4;
        #pragma unroll
        for (int s = 0; s < 4; ++s) {
            bf16x8 af = *(const bf16x8*)&wo1T[(size_t)(w * 16 + tx) * 128 + s * 32 + tg * 8];
            bf16x8 bfr[4];
            #pragma unroll
            for (int nt = 0; nt < 4; ++nt)
                bfr[nt] = *(const bf16x8*)&hb[(nt * 16 + tx) * 136 + s * 32 + tg * 8];
            #pragma unroll
            for (int nt = 0; nt < 4; ++nt)
                acc[nt] = __builtin_amdgcn_mfma_f32_16x16x32_bf16(af, bfr[nt], acc[nt], 0, 0, 0);
        }
        __syncthreads();          // tb LDS is dead; reuse as f32 hsum[4][64]
        float* hsum = (float*)tb;
        #pragma unroll
        for (int nt = 0; nt < 4; ++nt) {
            int c0 = w * 16 + tg * 4;
            float4 b1v = *(const float4*)&bo1[c0];
            float4 w2v = *(const float4*)&wo2[c0];
            float pl = sspf(acc[nt][0] + b1v.x) * w2v.x
                     + sspf(acc[nt][1] + b1v.y) * w2v.y
                     + sspf(acc[nt][2] + b1v.z) * w2v.z
                     + sspf(acc[nt][3] + b1v.w) * w2v.w;
            pl += __shfl_xor(pl, 16);
            pl += __shfl_xor(pl, 32);
            if (tg == 0) hsum[w * 64 + nt * 16 + tx] = pl;
        }
        __syncthreads();
        if (t < 64) {
            int n = n0 + t;
            if (n < nrows)
                outp[n] = hsum[t] + hsum[64 + t] + hsum[128 + t] + hsum[192 + t] + bo2[0];
        }
    }
}

// ---------------- node-centric edge aggregation --------------------------------
// One wave per dst node; 2 channels/lane. Edges sorted far-first per node.
// Far edge (d>=DMAX): ep folded into kvw biases -> 1 kv gather + dot + exp.
// Near edge: + bf16 delta-table lerp. q pre-scaled by 0.25*log2(e); exp2f.
// Output t is packed bf16 pairs. Far loop 8-deep (VGPR 32 -> high occupancy;
// 16-deep raised VGPR to 48, occupancy 54->37%, net loss: round 21).
__global__ __launch_bounds__(256) void k_agg(
    const int* __restrict__ rowptr, const int* __restrict__ rowmid,
    const int* __restrict__ srcp, const int2* __restrict__ erec,
    const uint2* __restrict__ tabq, const float* __restrict__ qn,
    const unsigned int* __restrict__ kvw, const float* __restrict__ skip,
    unsigned int* __restrict__ tout)
{
    int wid0 = (blockIdx.x * 256 + threadIdx.x) >> 6;   // node id
    if (wid0 >= NN) return;
    const int wid = __builtin_amdgcn_readfirstlane(wid0);   // SGPR -> scalar loads
    const int ln = threadIdx.x & 63;
    const int c0 = ln * 2;   // head = ln>>3
    const float SC = 0.25f * 1.4426950408889634f;
    float2 q2 = *(const float2*)&qn[(size_t)wid * CC + c0];
    q2.x *= SC; q2.y *= SC;
    float nx = 0.0f, ny = 0.0f, den = 0.0f;
    int e = rowptr[wid];
    const int emid = rowmid[wid];
    const int eend = rowptr[wid + 1];
    const float FS = 1.52587890625e-5f;   // 1/65536

    auto edgeF = [&](uint2 kv) {
        float kex = __uint_as_float(kv.x << 16);
        float key = __uint_as_float(kv.x & 0xffff0000u);
        float vex = __uint_as_float(kv.y << 16);
        float vey = __uint_as_float(kv.y & 0xffff0000u);
        float p = fmaf(q2.x, kex, q2.y * key);
        p += __shfl_xor(p, 1);
        p += __shfl_xor(p, 2);
        p += __shfl_xor(p, 4);          // sum over the head's 16 channels
        float w = exp2f(p);
        nx = fmaf(w, vex, nx);
        ny = fmaf(w, vey, ny);
        den += w;
    };
    auto edgeN = [&](uint2 kv, uint2 tp, float fr) {
        float t0x = __uint_as_float(tp.x << 16);
        float t0y = __uint_as_float(tp.x & 0xffff0000u);
        float t1x = __uint_as_float(tp.y << 16);
        float t1y = __uint_as_float(tp.y & 0xffff0000u);
        float ex = fmaf(fr, t1x - t0x, t0x);
        float ey = fmaf(fr, t1y - t0y, t0y);
        float kex = __uint_as_float(kv.x << 16) + ex;
        float key = __uint_as_float(kv.x & 0xffff0000u) + ey;
        float vex = __uint_as_float(kv.y << 16) + ex;
        float vey = __uint_as_float(kv.y & 0xffff0000u) + ey;
        float p = fmaf(q2.x, kex, q2.y * key);
        p += __shfl_xor(p, 1);
        p += __shfl_xor(p, 2);
        p += __shfl_xor(p, 4);
        float w = exp2f(p);
        nx = fmaf(w, vex, nx);
        ny = fmaf(w, vey, ny);
        den += w;
    };

    // ---- far edges, 8-deep ----
    for (; e + 8 <= emid; e += 8) {
        int s0 = srcp[e + 0], s1 = srcp[e + 1], s2 = srcp[e + 2], s3 = srcp[e + 3];
        int s4 = srcp[e + 4], s5 = srcp[e + 5], s6 = srcp[e + 6], s7 = srcp[e + 7];
        uint2 kv0 = *(const uint2*)&kvw[(size_t)s0 * 128 + c0];
        uint2 kv1 = *(const uint2*)&kvw[(size_t)s1 * 128 + c0];
        uint2 kv2 = *(const uint2*)&kvw[(size_t)s2 * 128 + c0];
        uint2 kv3 = *(const uint2*)&kvw[(size_t)s3 * 128 + c0];
        uint2 kv4 = *(const uint2*)&kvw[(size_t)s4 * 128 + c0];
        uint2 kv5 = *(const uint2*)&kvw[(size_t)s5 * 128 + c0];
        uint2 kv6 = *(const uint2*)&kvw[(size_t)s6 * 128 + c0];
        uint2 kv7 = *(const uint2*)&kvw[(size_t)s7 * 128 + c0];
        edgeF(kv0); edgeF(kv1); edgeF(kv2); edgeF(kv3);
        edgeF(kv4); edgeF(kv5); edgeF(kv6); edgeF(kv7);
    }
    for (; e < emid; ++e) {
        uint2 kv = *(const uint2*)&kvw[(size_t)srcp[e] * 128 + c0];
        edgeF(kv);
    }
    // ---- near edges, 4-deep ----
    for (; e + 4 <= eend; e += 4) {
        int2 r0 = erec[e + 0], r1 = erec[e + 1], r2 = erec[e + 2], r3 = erec[e + 3];
        uint2 kv0 = *(const uint2*)&kvw[(size_t)r0.x * 128 + c0];
        uint2 kv1 = *(const uint2*)&kvw[(size_t)r1.x * 128 + c0];
        uint2 kv2 = *(const uint2*)&kvw[(size_t)r2.x * 128 + c0];
        uint2 kv3 = *(const uint2*)&kvw[(size_t)r3.x * 128 + c0];
        uint2 tp0 = tabq[(size_t)(r0.y >> 16) * 64 + ln];
        uint2 tp1 = tabq[(size_t)(r1.y >> 16) * 64 + ln];
        uint2 tp2 = tabq[(size_t)(r2.y >> 16) * 64 + ln];
        uint2 tp3 = tabq[(size_t)(r3.y >> 16) * 64 + ln];
        edgeN(kv0, tp0, (float)(r0.y & 0xffff) * FS);
        edgeN(kv1, tp1, (float)(r1.y & 0xffff) * FS);
        edgeN(kv2, tp2, (float)(r2.y & 0xffff) * FS);
        edgeN(kv3, tp3, (float)(r3.y & 0xffff) * FS);
    }
    for (; e < eend; ++e) {
        int2 r = erec[e];
        uint2 kv = *(const uint2*)&kvw[(size_t)r.x * 128 + c0];
        uint2 tp = tabq[(size_t)(r.y >> 16) * 64 + ln];
        edgeN(kv, tp, (float)(r.y & 0xffff) * FS);
    }

    const float2 sk = *(const float2*)&skip[(size_t)wid * CC + c0];
    float inv = 1.0f / (den + 1e-16f);
    float ox = sspf(fmaf(nx, inv, sk.x));
    float oy = sspf(fmaf(ny, inv, sk.y));
    tout[(size_t)wid * 64 + ln] = (unsigned)f2bf(ox) | ((unsigned)f2bf(oy) << 16);
}

extern "C" void kernel_launch(void* const* d_in, const int* in_sizes, int n_in,
                              void* d_out, int out_size, void* d_ws, size_t ws_size,
                              hipStream_t stream)
{
    const int*   z   = (const int*)d_in[0];
    const float* pos = (const float*)d_in[1];
    const int*   ei  = (const int*)d_in[2];
    const float* emb = (const float*)d_in[3];
    const float* w1  = (const float*)d_in[4];
    const float* b1  = (const float*)d_in[5];
    const float* w2  = (const float*)d_in[6];
    const float* b2  = (const float*)d_in[7];
    const float* wq  = (const float*)d_in[8];
    const float* bq  = (const float*)d_in[9];
    const float* wk  = (const float*)d_in[10];
    const float* bk  = (const float*)d_in[11];
    const float* wv  = (const float*)d_in[12];
    const float* bv  = (const float*)d_in[13];
    const float* we  = (const float*)d_in[14];
    const float* be  = (const float*)d_in[15];
    const float* wsk = (const float*)d_in[16];
    const float* bsk = (const float*)d_in[17];
    const float* wl  = (const float*)d_in[18];
    const float* bl  = (const float*)d_in[19];
    const float* wo1 = (const float*)d_in[20];
    const float* bo1 = (const float*)d_in[21];
    const float* wo2 = (const float*)d_in[22];
    const float* bo2 = (const float*)d_in[23];

    char* p = (char*)d_ws;
    auto alloc = [&](size_t bytes) -> void* {
        void* r = (void*)p; p += (bytes + 255) & ~(size_t)255; return r;
    };
    float* h    = (float*)alloc((size_t)NN * CC * 4);
    float* q    = (float*)alloc((size_t)NN * CC * 4);
    float* skip = (float*)alloc((size_t)NN * CC * 4);
    unsigned int* tbp = (unsigned int*)alloc((size_t)NN * 64 * 4);   // packed bf16 t
    unsigned int* kvw = (unsigned int*)alloc((size_t)NN * 128 * 4);  // bf16 k/v pairs
    float4* pos4 = (float4*)alloc((size_t)NN * 16);
    float* w23f = (float*)alloc((size_t)LL * FF * CC * 4);
    float* b23g = (float*)alloc((size_t)LL * CC * 4);
    float* tab  = (float*)alloc((size_t)LL * (NTAB + 1) * CC * 4);
    uint2* tabq = (uint2*)alloc((size_t)LL * NTAB * 64 * 8);
    float* bkf  = (float*)alloc((size_t)LL * CC * 4);
    float* bvf  = (float*)alloc((size_t)LL * CC * 4);
    u16*   wn   = (u16*)alloc(((size_t)LL * 5 * 128 * 128 + 64 * 128) * 2);
    int* packed = (int*)alloc((size_t)NN * PSTR * 4);   // 128B line per counter
    int* pref   = (int*)alloc((size_t)NN * 4);
    int* bsum   = (int*)alloc((size_t)NB * 4);
    int* rowptr = (int*)alloc((size_t)(NN + 1) * 4);
    int* rowmid = (int*)alloc((size_t)NN * 4);
    int* srcp   = (int*)alloc((size_t)NE * 4);
    int2* rec2  = (int2*)alloc((size_t)NE * 8);
    int2* erec  = (int2*)alloc((size_t)NE * 8);

    k_pos4<<<(NN + 255) / 256, 256, 0, stream>>>(pos, pos4, packed);
    k_dist<<<(NE / 4 + 255) / 256, 256, 0, stream>>>(ei, pos4, packed, rec2);
    k_scan1<<<NB, 256, 0, stream>>>(packed, pref, bsum);
    k_scan2<<<NB, 256, 0, stream>>>(packed, pref, bsum, rowptr, rowmid);
    k_scatter<<<(NE / 4 + 255) / 256, 256, 0, stream>>>(ei, rec2, rowptr, rowmid, srcp, erec);
    k_prep23<<<LL * 128, 128, 0, stream>>>(w2, we, w23f);
    k_prepb<<<LL, 128, 0, stream>>>(b2, we, be, b23g);
    k_prept<<<LL * (NTAB + 1), 128, 0, stream>>>(w1, b1, w23f, b23g, tab);
    k_packt<<<(LL * NTAB * 64 + 255) / 256, 256, 0, stream>>>(tab, tabq);
    k_foldb<<<LL, 128, 0, stream>>>(bk, bv, tab, bkf, bvf);
    k_prepn<<<(LL * 5 * 128 * 128 + 64 * 128 + 255) / 256, 256, 0, stream>>>(
        wq, wk, wv, wsk, wl, wo1, wn);

    const u16* wo1T = wn + (size_t)LL * 5 * 16384;
    const int NT = (NN + 63) / 64;   // 313
    // layer 0 q/k/v/skip from emb[z] (writes h too)
    k_node<0><<<NT, 256, 0, stream>>>(z, emb, nullptr, nullptr, nullptr, h,
        wn, bq, bkf, bvf, bsk, q, kvw, skip,
        nullptr, nullptr, nullptr, nullptr, nullptr, NN);
    for (int l = 0; l < LL; ++l) {
        k_agg<<<(NN * 64 + 255) / 256, 256, 0, stream>>>(rowptr, rowmid, srcp, erec,
            tabq + (size_t)l * NTAB * 64, q, kvw, skip, tbp);
        const u16* wnl = wn + (size_t)l * 5 * 16384;
        if (l < LL - 1) {
            const u16* wnn = wn + (size_t)(l + 1) * 5 * 16384;
            k_node<1><<<NT, 256, 0, stream>>>(nullptr, nullptr, tbp,
                wnl + 4 * 16384, bl + l * CC, h,
                wnn, bq + (l + 1) * CC, bkf + (l + 1) * CC,
                bvf + (l + 1) * CC, bsk + (l + 1) * CC,
                q, kvw, skip,
                nullptr, nullptr, nullptr, nullptr, nullptr, NN);
        } else {
            k_node<2><<<NT, 256, 0, stream>>>(nullptr, nullptr, tbp,
                wnl + 4 * 16384, bl + l * CC, h,
                nullptr, nullptr, nullptr, nullptr, nullptr,
                nullptr, nullptr, nullptr,
                wo1T, bo1, wo2, bo2, (float*)d_out, NN);
        }
    }
}